// Round 1
// baseline (496.871 us; speedup 1.0000x reference)
//
#include <hip/hip_runtime.h>
#include <hip/hip_cooperative_groups.h>
#include <cmath>

namespace cg = cooperative_groups;

#define NA 8400
#define NC 80
#define BS 16
#define NMAX 64
#define TOPKK 13
#define CAP 768
#define CEPS 1e-9f
#define PIF 3.14159265358979323846f

// d_out layout (float32, concatenated)
#define OFF_LABELS  0
#define OFF_CIRCLES 134400
#define OFF_SCORES  537600
#define OFF_FG      11289600
#define OFF_TGI     11424000

// workspace layout (bytes)
//   colbits : [0, 1075200)           134400 x u64  (bit j set => mask_pos[b,j,a]=1)
//   posal   : [1075200, 1079296)     1024 x u32
//   posov   : [1079296, 1083392)     1024 x u32
//   tgiE    : [1083392, 1620992)     134400 x i32
//   alignv  : [1620992, 2158592)     134400 x f32
#define WS_POSAL   1075200
#define WS_POSOV   1079296
#define WS_TGI     1083392
#define WS_ALIGN   1620992
#define ZERO1_F4   67712      // (colbits+posal+posov)/16
#define ZERO2_F4   2688000    // target_scores floats /4

#define NBLK 1024
#define NTHR 256
#define GRIDTHREADS (NBLK * NTHR)

__device__ __forceinline__ float circle_iou_dev(float gx, float gy, float r1,
                                                float px, float py, float r2) {
    float dx = gx - px, dy = gy - py;
    float d = sqrtf(dx * dx + dy * dy + CEPS);
    float a1 = PIF * r1 * r1, a2 = PIF * r2 * r2;
    float d2 = d * d;
    float c1 = (d2 + r1 * r1 - r2 * r2) / (2.0f * d * r1 + CEPS);
    float c2 = (d2 + r2 * r2 - r1 * r1) / (2.0f * d * r2 + CEPS);
    c1 = fminf(fmaxf(c1, -1.0f), 1.0f);
    c2 = fminf(fmaxf(c2, -1.0f), 1.0f);
    float tri = fmaxf((r1 + r2 - d) * (d + r1 - r2) * (d - r1 + r2) * (d + r1 + r2), 0.0f);
    float lens = r1 * r1 * acosf(c1) + r2 * r2 * acosf(c2) - 0.5f * sqrtf(tri);
    float inter;
    if (d >= r1 + r2)             inter = 0.0f;
    else if (d <= fabsf(r1 - r2)) { float rm = fminf(r1, r2); inter = PIF * rm * rm; }
    else                          inter = lens;
    return inter / (a1 + a2 - inter + CEPS);
}

// Single cooperative kernel.
// P0: zero colbits+posal+posov (ws) and target_scores (out)
// P1: per-block (b,j) bbox-enumerated candidates, dense align, 13-pass argmax,
//     zero-filler per reference top_k tie semantics, emit bits into colbits.
// P2: per-anchor resolve (contested -> overlap argmax), outputs, posal/posov.
// P3: scatter norm into target_scores[b, a, label].
__global__ __launch_bounds__(256, 4) void fused(
    const float* __restrict__ pd_scores, const float* __restrict__ pd_circles,
    const float* __restrict__ anc, const int* __restrict__ gt_labels,
    const float* __restrict__ gt_bboxes, const float* __restrict__ mask_gt,
    float* __restrict__ out, char* __restrict__ wsb)
{
    cg::grid_group grid = cg::this_grid();

    unsigned long long* colbits = (unsigned long long*)wsb;
    unsigned int* posal = (unsigned int*)(wsb + WS_POSAL);
    unsigned int* posov = (unsigned int*)(wsb + WS_POSOV);
    int*   tgiE   = (int*)(wsb + WS_TGI);
    float* alignv = (float*)(wsb + WS_ALIGN);

    __shared__ int   s_cidx[CAP];
    __shared__ float s_cval[CAP];
    __shared__ float s_low[64];            // align of anchors 0..63 (0 default)
    __shared__ unsigned long long s_ingt0; // in-gt bits for anchors 0..63
    __shared__ int   s_ncand, s_nsel, s_done;
    __shared__ float s_redv[4];
    __shared__ int   s_redi[4], s_redc[4];
    __shared__ int   s_sel[16];

    const int t = threadIdx.x;
    const int gtid = blockIdx.x * NTHR + t;
    const int lane = t & 63, wv = t >> 6;

    // ---------------- P0: zero ws + target_scores ----------------
    {
        const float4 z = make_float4(0.f, 0.f, 0.f, 0.f);
        float4* wsz = (float4*)wsb;
        float4* sc4 = (float4*)(out + OFF_SCORES);
        for (int i = gtid; i < ZERO2_F4; i += GRIDTHREADS) sc4[i] = z;
        for (int i = gtid; i < ZERO1_F4; i += GRIDTHREADS) wsz[i] = z;
    }
    grid.sync();

    // ---------------- P1: top-13 selection per (b, j) ----------------
    {
        const int row = blockIdx.x;            // b*64 + j
        const int b = row >> 6, j = row & 63;

        if (mask_gt[row] > 0.0f) {             // uniform per block
            const float gx = gt_bboxes[row * 3 + 0];
            const float gy = gt_bboxes[row * 3 + 1];
            const float gr = gt_bboxes[row * 3 + 2];
            int lab = gt_labels[row];
            lab = min(max(lab, 0), NC - 1);

            if (t == 0) { s_ncand = 0; s_nsel = 0; s_done = 0; }
            if (t < 64) s_low[t] = 0.0f;
            __syncthreads();

            // in-gt bits for anchors 0..63 (level-0 row 0: x=(i+0.5)*8, y=4)
            if (wv == 0) {
                float ax = ((float)lane + 0.5f) * 8.0f, ay = 4.0f;
                float dx = gx - ax, dy = gy - ay;
                bool in0 = (sqrtf(dx * dx + dy * dy) <= gr);
                unsigned long long m = __ballot(in0);
                if (lane == 0) s_ingt0 = m;
            }

            // phase A: analytic bbox enumeration (exact membership test kept).
            // Anchor coords (i+0.5)*s are bit-identical to the anc table
            // (s is a power of two).
            const int strides_[3] = {8, 16, 32};
            const int ns_[3]      = {80, 40, 20};
            const int bases_[3]   = {0, 6400, 8000};
#pragma unroll
            for (int l = 0; l < 3; ++l) {
                const float sl = (float)strides_[l];
                const int n_l = ns_[l], base_l = bases_[l];
                const float inv = 1.0f / sl;
                int y0 = (int)ceilf((gy - gr) * inv - 0.5f) - 1;
                int y1 = (int)floorf((gy + gr) * inv - 0.5f) + 1;
                int x0 = (int)ceilf((gx - gr) * inv - 0.5f) - 1;
                int x1 = (int)floorf((gx + gr) * inv - 0.5f) + 1;
                y0 = max(y0, 0); x0 = max(x0, 0);
                y1 = min(y1, n_l - 1); x1 = min(x1, n_l - 1);
                const int W = x1 - x0 + 1, H = y1 - y0 + 1;
                if (W > 0 && H > 0) {
                    const int cells = W * H;
                    for (int c = t; c < cells; c += NTHR) {
                        const int q = c / W;
                        const int iy = y0 + q, ix = x0 + (c - q * W);
                        float ax = ((float)ix + 0.5f) * sl;
                        float ay = ((float)iy + 0.5f) * sl;
                        float dx = gx - ax, dy = gy - ay;
                        if (sqrtf(dx * dx + dy * dy) <= gr) {
                            int p = atomicAdd(&s_ncand, 1);
                            if (p < CAP) s_cidx[p] = base_l + iy * n_l + ix;
                        }
                    }
                }
            }
            __syncthreads();
            const int n = min(s_ncand, CAP);

            // phase B: dense align compute over candidates
            for (int c = t; c < n; c += NTHR) {
                int a = s_cidx[c];
                size_t pi = (size_t)(b * NA + a);
                float px = pd_circles[pi * 3 + 0];
                float py = pd_circles[pi * 3 + 1];
                float pr = pd_circles[pi * 3 + 2];
                float iou = circle_iou_dev(gx, gy, gr, px, py, pr);
                float sc  = pd_scores[pi * NC + lab];
                float o2 = iou * iou;
                float v = sc * (o2 * o2 * o2);
                s_cval[c] = v;
                if (a < 64) s_low[a] = v;
            }
            __syncthreads();

            // phase C: 13-pass argmax (value desc, anchor-idx asc)
            for (int it = 0; it < TOPKK; ++it) {
                float bv = -1.0f; int bi = 1 << 30, bc = -1;
                for (int c = t; c < n; c += NTHR) {
                    float v = s_cval[c]; int a = s_cidx[c];
                    if (v > bv || (v == bv && a < bi)) { bv = v; bi = a; bc = c; }
                }
                for (int off = 32; off > 0; off >>= 1) {
                    float ov = __shfl_down(bv, off);
                    int   oi = __shfl_down(bi, off);
                    int   oc = __shfl_down(bc, off);
                    if (ov > bv || (ov == bv && oi < bi)) { bv = ov; bi = oi; bc = oc; }
                }
                if (lane == 0) { s_redv[wv] = bv; s_redi[wv] = bi; s_redc[wv] = bc; }
                __syncthreads();
                if (t == 0) {
                    float vb = s_redv[0]; int ib = s_redi[0], cb = s_redc[0];
                    for (int w = 1; w < 4; ++w)
                        if (s_redv[w] > vb || (s_redv[w] == vb && s_redi[w] < ib))
                            { vb = s_redv[w]; ib = s_redi[w]; cb = s_redc[w]; }
                    if (vb > 0.0f) { s_sel[s_nsel] = ib; s_nsel++; s_cval[cb] = -1.0f; }
                    else s_done = 1;
                }
                __syncthreads();
                if (s_done) break;
            }

            // phase D: zero-filler — reference top_k fills remaining slots with
            // the globally lowest-index zero-valued entries; keep in-gt ones.
            if (t == 0) {
                int r = TOPKK - s_nsel;
                if (r > 0) {
                    for (int idx = 0; idx < 64 && r > 0; ++idx) {
                        if (s_low[idx] > 0.0f) continue;
                        r--;
                        if ((s_ingt0 >> idx) & 1ull) { s_sel[s_nsel] = idx; s_nsel++; }
                    }
                }
            }
            __syncthreads();

            // phase E: set bit j in each selected anchor's GT column
            if (t < s_nsel)
                atomicOr(&colbits[(size_t)b * NA + s_sel[t]], 1ull << j);
        }
    }
    grid.sync();

    // ---------------- P2: per-anchor resolve ----------------
    if (gtid < BS * NA) {
        const int idx = gtid;
        const int b = idx / NA;
        const int a = idx - b * NA;

        const unsigned long long col = colbits[idx];
        const int cnt = __popcll(col);

        int tgi = 0, fg = 0;
        if (cnt == 1) { fg = 1; tgi = __ffsll((unsigned long long)col) - 1; }
        else if (cnt > 1) {
            fg = 1;
            float px = pd_circles[(size_t)idx * 3 + 0];
            float py = pd_circles[(size_t)idx * 3 + 1];
            float pr = pd_circles[(size_t)idx * 3 + 2];
            float ax = anc[2 * a], ay = anc[2 * a + 1];
            float bo = -1.0f; int bj = 0;
            for (int j = 0; j < NMAX; ++j) {
                float mgv = mask_gt[b * NMAX + j];
                float gx = gt_bboxes[(b * NMAX + j) * 3 + 0];
                float gy = gt_bboxes[(b * NMAX + j) * 3 + 1];
                float gr = gt_bboxes[(b * NMAX + j) * 3 + 2];
                float ovj = 0.0f;
                if (mgv > 0.0f) {
                    float dx = gx - ax, dy = gy - ay;
                    if (sqrtf(dx * dx + dy * dy) <= gr)
                        ovj = circle_iou_dev(gx, gy, gr, px, py, pr);
                }
                if (ovj > bo) { bo = ovj; bj = j; }  // strict >: first-max
            }
            tgi = bj;
        }

        const int gl = gt_labels[b * NMAX + tgi];
        const float gx = gt_bboxes[(b * NMAX + tgi) * 3 + 0];
        const float gy = gt_bboxes[(b * NMAX + tgi) * 3 + 1];
        const float gr = gt_bboxes[(b * NMAX + tgi) * 3 + 2];

        out[OFF_LABELS + idx] = (float)max(gl, 0);
        out[OFF_CIRCLES + (size_t)idx * 3 + 0] = gx;
        out[OFF_CIRCLES + (size_t)idx * 3 + 1] = gy;
        out[OFF_CIRCLES + (size_t)idx * 3 + 2] = gr;
        out[OFF_FG + idx]  = (float)fg;
        out[OFF_TGI + idx] = (float)tgi;
        tgiE[idx] = fg ? tgi : -1;

        float alg = 0.0f;
        if (fg) {
            float ovv = 0.0f;
            float mgv = mask_gt[b * NMAX + tgi];
            float ax = anc[2 * a], ay = anc[2 * a + 1];
            float dx = gx - ax, dy = gy - ay;
            if (mgv > 0.0f && sqrtf(dx * dx + dy * dy) <= gr) {
                float px = pd_circles[(size_t)idx * 3 + 0];
                float py = pd_circles[(size_t)idx * 3 + 1];
                float pr = pd_circles[(size_t)idx * 3 + 2];
                float iou = circle_iou_dev(gx, gy, gr, px, py, pr);
                int lab = min(max(gl, 0), NC - 1);
                float sc = pd_scores[((size_t)b * NA + a) * NC + lab];
                ovv = iou;
                float o2 = iou * iou;
                alg = sc * (o2 * o2 * o2);
            }
            atomicMax(&posal[b * NMAX + tgi], __float_as_uint(alg));
            atomicMax(&posov[b * NMAX + tgi], __float_as_uint(ovv));
        }
        alignv[idx] = alg;
    }
    grid.sync();

    // ---------------- P3: scatter norm into target_scores ----------------
    if (gtid < BS * NA) {
        const int idx = gtid;
        int tg = tgiE[idx];
        if (tg >= 0) {
            int b = idx / NA;
            float pa = __uint_as_float(posal[b * NMAX + tg]);
            float po = __uint_as_float(posov[b * NMAX + tg]);
            float norm = alignv[idx] * po / (pa + CEPS);
            int lab = max(gt_labels[b * NMAX + tg], 0);
            out[OFF_SCORES + (size_t)idx * NC + lab] = norm;
        }
    }
}

extern "C" void kernel_launch(void* const* d_in, const int* in_sizes, int n_in,
                              void* d_out, int out_size, void* d_ws, size_t ws_size,
                              hipStream_t stream) {
    const float* pd_scores  = (const float*)d_in[0];
    const float* pd_circles = (const float*)d_in[1];
    const float* anc        = (const float*)d_in[2];
    const int*   gt_labels  = (const int*)d_in[3];
    const float* gt_bboxes  = (const float*)d_in[4];
    const float* mask_gt    = (const float*)d_in[5];
    float* out = (float*)d_out;
    char*  ws  = (char*)d_ws;

    void* kargs[8];
    kargs[0] = (void*)&pd_scores;
    kargs[1] = (void*)&pd_circles;
    kargs[2] = (void*)&anc;
    kargs[3] = (void*)&gt_labels;
    kargs[4] = (void*)&gt_bboxes;
    kargs[5] = (void*)&mask_gt;
    kargs[6] = (void*)&out;
    kargs[7] = (void*)&ws;

    hipLaunchCooperativeKernel((const void*)fused, dim3(NBLK), dim3(NTHR),
                               kargs, 0, stream);
}

// Round 2
// 170.577 us; speedup vs baseline: 2.9129x; 2.9129x over previous
//
#include <hip/hip_runtime.h>
#include <cmath>

#define NA 8400
#define NC 80
#define BS 16
#define NMAX 64
#define TOPKK 13
#define CAP 768
#define CEPS 1e-9f
#define PIF 3.14159265358979323846f

// d_out layout (float32, concatenated)
#define OFF_LABELS  0
#define OFF_CIRCLES 134400
#define OFF_SCORES  537600
#define OFF_FG      11289600
#define OFF_TGI     11424000

// workspace layout (bytes)
//   colbits : [0, 1075200)           134400 x u64  (bit j set => mask_pos[b,j,a]=1)
//   posal   : [1075200, 1079296)     1024 x u32
//   posov   : [1079296, 1083392)     1024 x u32
//   tgiE    : [1083392, 1620992)     134400 x i32
//   alignv  : [1620992, 2158592)     134400 x f32
#define WS_POSAL   1075200
#define WS_POSOV   1079296
#define WS_TGI     1083392
#define WS_ALIGN   1620992
#define ZERO_WS_F4 67712      // (colbits+posal+posov)/16

__device__ __forceinline__ float circle_iou_dev(float gx, float gy, float r1,
                                                float px, float py, float r2) {
    float dx = gx - px, dy = gy - py;
    float d = sqrtf(dx * dx + dy * dy + CEPS);
    float a1 = PIF * r1 * r1, a2 = PIF * r2 * r2;
    float d2 = d * d;
    float c1 = (d2 + r1 * r1 - r2 * r2) / (2.0f * d * r1 + CEPS);
    float c2 = (d2 + r2 * r2 - r1 * r1) / (2.0f * d * r2 + CEPS);
    c1 = fminf(fmaxf(c1, -1.0f), 1.0f);
    c2 = fminf(fmaxf(c2, -1.0f), 1.0f);
    float tri = fmaxf((r1 + r2 - d) * (d + r1 - r2) * (d - r1 + r2) * (d + r1 + r2), 0.0f);
    float lens = r1 * r1 * acosf(c1) + r2 * r2 * acosf(c2) - 0.5f * sqrtf(tri);
    float inter;
    if (d >= r1 + r2)             inter = 0.0f;
    else if (d <= fabsf(r1 - r2)) { float rm = fminf(r1, r2); inter = PIF * rm * rm; }
    else                          inter = lens;
    return inter / (a1 + a2 - inter + CEPS);
}

// K0: zero colbits + posal + posov only (1.08 MB). target_scores is now
// written densely by K4, so the 43 MB zero pass is gone.
__global__ __launch_bounds__(256) void k0_zero(float4* __restrict__ wsz)
{
    int i = blockIdx.x * 256 + threadIdx.x;
    if (i < ZERO_WS_F4) wsz[i] = make_float4(0.f, 0.f, 0.f, 0.f);
}

// K1: one block per (b, j). Analytic bbox enumeration of candidate anchors
// (exact fp32 membership test preserved — anchor coords (i+0.5)*s are
// bit-identical to the anc table since s is a power of two), dense align
// compute, 13-pass argmax with reference tie semantics, zero-filler, emit
// selected bits into per-anchor GT columns.
__global__ __launch_bounds__(256) void k1_topk(
    const float* __restrict__ pd_scores, const float* __restrict__ pd_circles,
    const int* __restrict__ gt_labels, const float* __restrict__ gt_bboxes,
    const float* __restrict__ mask_gt, unsigned long long* __restrict__ colbits)
{
    __shared__ int   s_cidx[CAP];
    __shared__ float s_cval[CAP];
    __shared__ float s_low[64];            // align of anchors 0..63 (0 default)
    __shared__ unsigned long long s_ingt0; // in-gt bits for anchors 0..63
    __shared__ int   s_ncand, s_nsel, s_done;
    __shared__ float s_redv[4];
    __shared__ int   s_redi[4], s_redc[4];
    __shared__ int   s_sel[16];

    const int row = blockIdx.x;            // b*64 + j
    const int b = row >> 6, j = row & 63;
    const int t = threadIdx.x;
    const int lane = t & 63, wv = t >> 6;

    if (mask_gt[row] <= 0.0f) return;      // colbits pre-zeroed by K0

    const float gx = gt_bboxes[row * 3 + 0];
    const float gy = gt_bboxes[row * 3 + 1];
    const float gr = gt_bboxes[row * 3 + 2];
    int lab = gt_labels[row];
    lab = min(max(lab, 0), NC - 1);

    if (t == 0) { s_ncand = 0; s_nsel = 0; s_done = 0; }
    if (t < 64) s_low[t] = 0.0f;
    __syncthreads();

    // in-gt bits for anchors 0..63 (level-0 row 0: x=(i+0.5)*8, y=4)
    if (wv == 0) {
        float ax = ((float)lane + 0.5f) * 8.0f, ay = 4.0f;
        float dx = gx - ax, dy = gy - ay;
        bool in0 = (sqrtf(dx * dx + dy * dy) <= gr);
        unsigned long long m = __ballot(in0);
        if (lane == 0) s_ingt0 = m;
    }

    // phase A: analytic bbox enumeration + exact membership test
    const int strides_[3] = {8, 16, 32};
    const int ns_[3]      = {80, 40, 20};
    const int bases_[3]   = {0, 6400, 8000};
#pragma unroll
    for (int l = 0; l < 3; ++l) {
        const float sl = (float)strides_[l];
        const int n_l = ns_[l], base_l = bases_[l];
        const float inv = 1.0f / sl;
        int y0 = (int)ceilf((gy - gr) * inv - 0.5f) - 1;
        int y1 = (int)floorf((gy + gr) * inv - 0.5f) + 1;
        int x0 = (int)ceilf((gx - gr) * inv - 0.5f) - 1;
        int x1 = (int)floorf((gx + gr) * inv - 0.5f) + 1;
        y0 = max(y0, 0); x0 = max(x0, 0);
        y1 = min(y1, n_l - 1); x1 = min(x1, n_l - 1);
        const int W = x1 - x0 + 1, H = y1 - y0 + 1;
        if (W > 0 && H > 0) {
            const int cells = W * H;
            for (int c = t; c < cells; c += 256) {
                const int q = c / W;
                const int iy = y0 + q, ix = x0 + (c - q * W);
                float ax = ((float)ix + 0.5f) * sl;
                float ay = ((float)iy + 0.5f) * sl;
                float dx = gx - ax, dy = gy - ay;
                if (sqrtf(dx * dx + dy * dy) <= gr) {
                    int p = atomicAdd(&s_ncand, 1);
                    if (p < CAP) s_cidx[p] = base_l + iy * n_l + ix;
                }
            }
        }
    }
    __syncthreads();
    const int n = min(s_ncand, CAP);

    // phase B: dense align compute over candidates
    for (int c = t; c < n; c += 256) {
        int a = s_cidx[c];
        size_t pi = (size_t)(b * NA + a);
        float px = pd_circles[pi * 3 + 0];
        float py = pd_circles[pi * 3 + 1];
        float pr = pd_circles[pi * 3 + 2];
        float iou = circle_iou_dev(gx, gy, gr, px, py, pr);
        float sc  = pd_scores[pi * NC + lab];
        float o2 = iou * iou;
        float v = sc * (o2 * o2 * o2);
        s_cval[c] = v;
        if (a < 64) s_low[a] = v;
    }
    __syncthreads();

    // phase C: 13-pass argmax (value desc, anchor-idx asc)
    for (int it = 0; it < TOPKK; ++it) {
        float bv = -1.0f; int bi = 1 << 30, bc = -1;
        for (int c = t; c < n; c += 256) {
            float v = s_cval[c]; int a = s_cidx[c];
            if (v > bv || (v == bv && a < bi)) { bv = v; bi = a; bc = c; }
        }
        for (int off = 32; off > 0; off >>= 1) {
            float ov = __shfl_down(bv, off);
            int   oi = __shfl_down(bi, off);
            int   oc = __shfl_down(bc, off);
            if (ov > bv || (ov == bv && oi < bi)) { bv = ov; bi = oi; bc = oc; }
        }
        if (lane == 0) { s_redv[wv] = bv; s_redi[wv] = bi; s_redc[wv] = bc; }
        __syncthreads();
        if (t == 0) {
            float vb = s_redv[0]; int ib = s_redi[0], cb = s_redc[0];
            for (int w = 1; w < 4; ++w)
                if (s_redv[w] > vb || (s_redv[w] == vb && s_redi[w] < ib))
                    { vb = s_redv[w]; ib = s_redi[w]; cb = s_redc[w]; }
            if (vb > 0.0f) { s_sel[s_nsel] = ib; s_nsel++; s_cval[cb] = -1.0f; }
            else s_done = 1;
        }
        __syncthreads();
        if (s_done) break;
    }

    // phase D: zero-filler — reference top_k fills remaining slots with the
    // globally lowest-index zero-valued entries; keep only in-gt ones.
    if (t == 0) {
        int r = TOPKK - s_nsel;
        if (r > 0) {
            for (int idx = 0; idx < 64 && r > 0; ++idx) {
                if (s_low[idx] > 0.0f) continue;   // positive candidate, skip
                r--;                                // consumes a zero slot
                if ((s_ingt0 >> idx) & 1ull) { s_sel[s_nsel] = idx; s_nsel++; }
            }
        }
    }
    __syncthreads();

    // phase E: set bit j in each selected anchor's GT column
    if (t < s_nsel)
        atomicOr(&colbits[(size_t)b * NA + s_sel[t]], 1ull << j);
}

// K2: one thread per (b, a). Resolve contested anchors by overlap argmax
// (first-max); write labels/circles/fg/tgi; posal/posov atomicMax.
__global__ __launch_bounds__(256) void k2_resolve(
    const float* __restrict__ pd_scores, const float* __restrict__ pd_circles,
    const float* __restrict__ anc, const int* __restrict__ gt_labels,
    const float* __restrict__ gt_bboxes, const float* __restrict__ mask_gt,
    const unsigned long long* __restrict__ colbits,
    float* __restrict__ out, int* __restrict__ tgiE, float* __restrict__ alignv,
    unsigned int* __restrict__ posal, unsigned int* __restrict__ posov)
{
    const int idx = blockIdx.x * 256 + threadIdx.x;   // < 134400
    const int b = idx / NA;
    const int a = idx - b * NA;

    const unsigned long long col = colbits[idx];
    const int cnt = __popcll(col);

    int tgi = 0, fg = 0;
    if (cnt == 1) { fg = 1; tgi = __ffsll((unsigned long long)col) - 1; }
    else if (cnt > 1) {
        fg = 1;
        float px = pd_circles[(size_t)idx * 3 + 0];
        float py = pd_circles[(size_t)idx * 3 + 1];
        float pr = pd_circles[(size_t)idx * 3 + 2];
        float ax = anc[2 * a], ay = anc[2 * a + 1];
        float bo = -1.0f; int bj = 0;
        for (int j = 0; j < NMAX; ++j) {
            float mgv = mask_gt[b * NMAX + j];
            float gx = gt_bboxes[(b * NMAX + j) * 3 + 0];
            float gy = gt_bboxes[(b * NMAX + j) * 3 + 1];
            float gr = gt_bboxes[(b * NMAX + j) * 3 + 2];
            float ovj = 0.0f;
            if (mgv > 0.0f) {
                float dx = gx - ax, dy = gy - ay;
                if (sqrtf(dx * dx + dy * dy) <= gr)
                    ovj = circle_iou_dev(gx, gy, gr, px, py, pr);
            }
            if (ovj > bo) { bo = ovj; bj = j; }  // strict >: first-max
        }
        tgi = bj;
    }

    const int gl = gt_labels[b * NMAX + tgi];
    const float gx = gt_bboxes[(b * NMAX + tgi) * 3 + 0];
    const float gy = gt_bboxes[(b * NMAX + tgi) * 3 + 1];
    const float gr = gt_bboxes[(b * NMAX + tgi) * 3 + 2];

    out[OFF_LABELS + idx] = (float)max(gl, 0);
    out[OFF_CIRCLES + (size_t)idx * 3 + 0] = gx;
    out[OFF_CIRCLES + (size_t)idx * 3 + 1] = gy;
    out[OFF_CIRCLES + (size_t)idx * 3 + 2] = gr;
    out[OFF_FG + idx]  = (float)fg;
    out[OFF_TGI + idx] = (float)tgi;
    tgiE[idx] = fg ? tgi : -1;

    float alg = 0.0f;
    if (fg) {
        float ovv = 0.0f;
        float mgv = mask_gt[b * NMAX + tgi];
        float ax = anc[2 * a], ay = anc[2 * a + 1];
        float dx = gx - ax, dy = gy - ay;
        if (mgv > 0.0f && sqrtf(dx * dx + dy * dy) <= gr) {
            float px = pd_circles[(size_t)idx * 3 + 0];
            float py = pd_circles[(size_t)idx * 3 + 1];
            float pr = pd_circles[(size_t)idx * 3 + 2];
            float iou = circle_iou_dev(gx, gy, gr, px, py, pr);
            int lab = min(max(gl, 0), NC - 1);
            float sc = pd_scores[((size_t)b * NA + a) * NC + lab];
            ovv = iou;
            float o2 = iou * iou;
            alg = sc * (o2 * o2 * o2);
        }
        atomicMax(&posal[b * NMAX + tgi], __float_as_uint(alg));
        atomicMax(&posov[b * NMAX + tgi], __float_as_uint(ovv));
    }
    alignv[idx] = alg;
}

// K4: dense write of target_scores — each float4 covers 4 classes of one
// anchor row; bg rows are zero, fg rows have norm at the label slot.
// Replaces the separate 43 MB zero pass.
__global__ __launch_bounds__(256) void k4_dense(
    const int* __restrict__ tgiE, const float* __restrict__ alignv,
    const unsigned int* __restrict__ posal, const unsigned int* __restrict__ posov,
    const int* __restrict__ gt_labels, float4* __restrict__ scores4)
{
    const int f = blockIdx.x * 256 + threadIdx.x;     // < 2,688,000
    const int a_idx = f / 20;                         // anchor global idx
    const int p = f - a_idx * 20;                     // float4 slot in row

    float4 v = make_float4(0.f, 0.f, 0.f, 0.f);
    const int tg = tgiE[a_idx];
    if (tg >= 0) {
        const int b = a_idx / NA;
        const float pa = __uint_as_float(posal[b * NMAX + tg]);
        const float po = __uint_as_float(posov[b * NMAX + tg]);
        const float norm = alignv[a_idx] * po / (pa + CEPS);
        const int lab = max(gt_labels[b * NMAX + tg], 0);
        if ((lab >> 2) == p) ((float*)&v)[lab & 3] = norm;
    }
    scores4[f] = v;
}

extern "C" void kernel_launch(void* const* d_in, const int* in_sizes, int n_in,
                              void* d_out, int out_size, void* d_ws, size_t ws_size,
                              hipStream_t stream) {
    const float* pd_scores  = (const float*)d_in[0];
    const float* pd_circles = (const float*)d_in[1];
    const float* anc        = (const float*)d_in[2];
    const int*   gt_labels  = (const int*)d_in[3];
    const float* gt_bboxes  = (const float*)d_in[4];
    const float* mask_gt    = (const float*)d_in[5];
    float* out = (float*)d_out;

    char* ws = (char*)d_ws;
    unsigned long long* colbits = (unsigned long long*)ws;
    unsigned int* posal = (unsigned int*)(ws + WS_POSAL);
    unsigned int* posov = (unsigned int*)(ws + WS_POSOV);
    int*   tgiE   = (int*)(ws + WS_TGI);
    float* alignv = (float*)(ws + WS_ALIGN);

    k0_zero<<<(ZERO_WS_F4 + 255) / 256, 256, 0, stream>>>((float4*)ws);
    k1_topk<<<BS * NMAX, 256, 0, stream>>>(pd_scores, pd_circles, gt_labels,
                                           gt_bboxes, mask_gt, colbits);
    k2_resolve<<<(BS * NA) / 256, 256, 0, stream>>>(pd_scores, pd_circles, anc,
                                                    gt_labels, gt_bboxes, mask_gt,
                                                    colbits, out, tgiE, alignv,
                                                    posal, posov);
    k4_dense<<<(BS * NA * NC / 4) / 256, 256, 0, stream>>>(tgiE, alignv, posal,
                                                           posov, gt_labels,
                                                           (float4*)(out + OFF_SCORES));
}

// Round 3
// 140.921 us; speedup vs baseline: 3.5259x; 1.2104x over previous
//
#include <hip/hip_runtime.h>
#include <cmath>

#define NA 8400
#define NC 80
#define BS 16
#define NMAX 64
#define TOPKK 13
#define CAP 768
#define CEPS 1e-9f
#define PIF 3.14159265358979323846f

// d_out layout (float32, concatenated)
#define OFF_LABELS  0
#define OFF_CIRCLES 134400
#define OFF_SCORES  537600
#define OFF_FG      11289600
#define OFF_TGI     11424000

// workspace layout (bytes)
//   colbits : [0, 1075200)           134400 x u64  (bit j set => mask_pos[b,j,a]=1)
//   ovkey   : [1075200, 2150400)     134400 x u64  (f32bits(iou)<<32 | (63-j))
//   posal   : [2150400, 2154496)     1024 x u32
//   posov   : [2154496, 2158592)     1024 x u32
//   tgiE    : [2158592, 2696192)     134400 x i32
//   alignv  : [2696192, 3233792)     134400 x f32
#define WS_OVKEY   1075200
#define WS_POSAL   2150400
#define WS_POSOV   2154496
#define WS_TGI     2158592
#define WS_ALIGN   2696192
#define ZERO_WS_F4 134912     // (colbits+ovkey+posal+posov)/16

__device__ __forceinline__ float circle_iou_dev(float gx, float gy, float r1,
                                                float px, float py, float r2) {
    float dx = gx - px, dy = gy - py;
    float d = sqrtf(dx * dx + dy * dy + CEPS);
    float a1 = PIF * r1 * r1, a2 = PIF * r2 * r2;
    float d2 = d * d;
    float c1 = (d2 + r1 * r1 - r2 * r2) / (2.0f * d * r1 + CEPS);
    float c2 = (d2 + r2 * r2 - r1 * r1) / (2.0f * d * r2 + CEPS);
    c1 = fminf(fmaxf(c1, -1.0f), 1.0f);
    c2 = fminf(fmaxf(c2, -1.0f), 1.0f);
    float tri = fmaxf((r1 + r2 - d) * (d + r1 - r2) * (d - r1 + r2) * (d + r1 + r2), 0.0f);
    float lens = r1 * r1 * acosf(c1) + r2 * r2 * acosf(c2) - 0.5f * sqrtf(tri);
    float inter;
    if (d >= r1 + r2)             inter = 0.0f;
    else if (d <= fabsf(r1 - r2)) { float rm = fminf(r1, r2); inter = PIF * rm * rm; }
    else                          inter = lens;
    return inter / (a1 + a2 - inter + CEPS);
}

// K0: zero colbits + ovkey + posal + posov (2.16 MB).
__global__ __launch_bounds__(256) void k0_zero(float4* __restrict__ wsz)
{
    int i = blockIdx.x * 256 + threadIdx.x;
    if (i < ZERO_WS_F4) wsz[i] = make_float4(0.f, 0.f, 0.f, 0.f);
}

// K1: one block per (b, j). Analytic bbox enumeration of candidate anchors
// (exact fp32 membership test preserved), dense align compute, publish
// per-anchor overlap-argmax key via atomicMax, 13-pass argmax with reference
// tie semantics, zero-filler, emit selected bits into per-anchor GT columns.
__global__ __launch_bounds__(256) void k1_topk(
    const float* __restrict__ pd_scores, const float* __restrict__ pd_circles,
    const int* __restrict__ gt_labels, const float* __restrict__ gt_bboxes,
    const float* __restrict__ mask_gt, unsigned long long* __restrict__ colbits,
    unsigned long long* __restrict__ ovkey)
{
    __shared__ int   s_cidx[CAP];
    __shared__ float s_cval[CAP];
    __shared__ float s_low[64];            // align of anchors 0..63 (0 default)
    __shared__ unsigned long long s_ingt0; // in-gt bits for anchors 0..63
    __shared__ int   s_ncand, s_nsel, s_done;
    __shared__ float s_redv[4];
    __shared__ int   s_redi[4], s_redc[4];
    __shared__ int   s_sel[16];

    const int row = blockIdx.x;            // b*64 + j
    const int b = row >> 6, j = row & 63;
    const int t = threadIdx.x;
    const int lane = t & 63, wv = t >> 6;

    if (mask_gt[row] <= 0.0f) return;      // ws pre-zeroed by K0

    const float gx = gt_bboxes[row * 3 + 0];
    const float gy = gt_bboxes[row * 3 + 1];
    const float gr = gt_bboxes[row * 3 + 2];
    int lab = gt_labels[row];
    lab = min(max(lab, 0), NC - 1);

    if (t == 0) { s_ncand = 0; s_nsel = 0; s_done = 0; }
    if (t < 64) s_low[t] = 0.0f;
    __syncthreads();

    // in-gt bits for anchors 0..63 (level-0 row 0: x=(i+0.5)*8, y=4)
    if (wv == 0) {
        float ax = ((float)lane + 0.5f) * 8.0f, ay = 4.0f;
        float dx = gx - ax, dy = gy - ay;
        bool in0 = (sqrtf(dx * dx + dy * dy) <= gr);
        unsigned long long m = __ballot(in0);
        if (lane == 0) s_ingt0 = m;
    }

    // phase A: analytic bbox enumeration + exact membership test
    const int strides_[3] = {8, 16, 32};
    const int ns_[3]      = {80, 40, 20};
    const int bases_[3]   = {0, 6400, 8000};
#pragma unroll
    for (int l = 0; l < 3; ++l) {
        const float sl = (float)strides_[l];
        const int n_l = ns_[l], base_l = bases_[l];
        const float inv = 1.0f / sl;
        int y0 = (int)ceilf((gy - gr) * inv - 0.5f) - 1;
        int y1 = (int)floorf((gy + gr) * inv - 0.5f) + 1;
        int x0 = (int)ceilf((gx - gr) * inv - 0.5f) - 1;
        int x1 = (int)floorf((gx + gr) * inv - 0.5f) + 1;
        y0 = max(y0, 0); x0 = max(x0, 0);
        y1 = min(y1, n_l - 1); x1 = min(x1, n_l - 1);
        const int W = x1 - x0 + 1, H = y1 - y0 + 1;
        if (W > 0 && H > 0) {
            const int cells = W * H;
            for (int c = t; c < cells; c += 256) {
                const int q = c / W;
                const int iy = y0 + q, ix = x0 + (c - q * W);
                float ax = ((float)ix + 0.5f) * sl;
                float ay = ((float)iy + 0.5f) * sl;
                float dx = gx - ax, dy = gy - ay;
                if (sqrtf(dx * dx + dy * dy) <= gr) {
                    int p = atomicAdd(&s_ncand, 1);
                    if (p < CAP) s_cidx[p] = base_l + iy * n_l + ix;
                }
            }
        }
    }
    __syncthreads();
    const int n = min(s_ncand, CAP);

    // phase B: dense align compute over candidates + overlap-argmax publish.
    // Key packs non-negative iou bits (order-preserving as unsigned) in the
    // high word and (63-j) in the low bits so equal-iou ties pick smallest j
    // — matching reference argmax first-max semantics.
    for (int c = t; c < n; c += 256) {
        int a = s_cidx[c];
        size_t pi = (size_t)(b * NA + a);
        float px = pd_circles[pi * 3 + 0];
        float py = pd_circles[pi * 3 + 1];
        float pr = pd_circles[pi * 3 + 2];
        float iou = circle_iou_dev(gx, gy, gr, px, py, pr);
        float sc  = pd_scores[pi * NC + lab];
        float o2 = iou * iou;
        float v = sc * (o2 * o2 * o2);
        s_cval[c] = v;
        if (a < 64) s_low[a] = v;
        unsigned long long key =
            ((unsigned long long)__float_as_uint(iou) << 32) |
            (unsigned long long)(63 - j);
        atomicMax(&ovkey[(size_t)b * NA + a], key);
    }
    __syncthreads();

    // phase C: 13-pass argmax (value desc, anchor-idx asc)
    for (int it = 0; it < TOPKK; ++it) {
        float bv = -1.0f; int bi = 1 << 30, bc = -1;
        for (int c = t; c < n; c += 256) {
            float v = s_cval[c]; int a = s_cidx[c];
            if (v > bv || (v == bv && a < bi)) { bv = v; bi = a; bc = c; }
        }
        for (int off = 32; off > 0; off >>= 1) {
            float ov = __shfl_down(bv, off);
            int   oi = __shfl_down(bi, off);
            int   oc = __shfl_down(bc, off);
            if (ov > bv || (ov == bv && oi < bi)) { bv = ov; bi = oi; bc = oc; }
        }
        if (lane == 0) { s_redv[wv] = bv; s_redi[wv] = bi; s_redc[wv] = bc; }
        __syncthreads();
        if (t == 0) {
            float vb = s_redv[0]; int ib = s_redi[0], cb = s_redc[0];
            for (int w = 1; w < 4; ++w)
                if (s_redv[w] > vb || (s_redv[w] == vb && s_redi[w] < ib))
                    { vb = s_redv[w]; ib = s_redi[w]; cb = s_redc[w]; }
            if (vb > 0.0f) { s_sel[s_nsel] = ib; s_nsel++; s_cval[cb] = -1.0f; }
            else s_done = 1;
        }
        __syncthreads();
        if (s_done) break;
    }

    // phase D: zero-filler — reference top_k fills remaining slots with the
    // globally lowest-index zero-valued entries; keep only in-gt ones.
    if (t == 0) {
        int r = TOPKK - s_nsel;
        if (r > 0) {
            for (int idx = 0; idx < 64 && r > 0; ++idx) {
                if (s_low[idx] > 0.0f) continue;   // positive candidate, skip
                r--;                                // consumes a zero slot
                if ((s_ingt0 >> idx) & 1ull) { s_sel[s_nsel] = idx; s_nsel++; }
            }
        }
    }
    __syncthreads();

    // phase E: set bit j in each selected anchor's GT column
    if (t < s_nsel)
        atomicOr(&colbits[(size_t)b * NA + s_sel[t]], 1ull << j);
}

// K2: one thread per (b, a). Contested anchors resolved by the precomputed
// overlap-argmax key (single 8B load — no 64-iteration loop); outputs +
// posal/posov atomicMax.
__global__ __launch_bounds__(256) void k2_resolve(
    const float* __restrict__ pd_scores, const float* __restrict__ pd_circles,
    const float* __restrict__ anc, const int* __restrict__ gt_labels,
    const float* __restrict__ gt_bboxes, const float* __restrict__ mask_gt,
    const unsigned long long* __restrict__ colbits,
    const unsigned long long* __restrict__ ovkey,
    float* __restrict__ out, int* __restrict__ tgiE, float* __restrict__ alignv,
    unsigned int* __restrict__ posal, unsigned int* __restrict__ posov)
{
    const int idx = blockIdx.x * 256 + threadIdx.x;   // < 134400
    const int b = idx / NA;
    const int a = idx - b * NA;

    const unsigned long long col = colbits[idx];
    const int cnt = __popcll(col);

    int tgi = 0, fg = 0;
    if (cnt == 1) { fg = 1; tgi = __ffsll((unsigned long long)col) - 1; }
    else if (cnt > 1) {
        fg = 1;
        const unsigned long long key = ovkey[idx];
        const unsigned int ib = (unsigned int)(key >> 32);
        // best iou == 0 -> reference row is all zeros -> argmax = 0
        tgi = (ib != 0u) ? (63 - (int)(key & 63ull)) : 0;
    }

    const int gl = gt_labels[b * NMAX + tgi];
    const float gx = gt_bboxes[(b * NMAX + tgi) * 3 + 0];
    const float gy = gt_bboxes[(b * NMAX + tgi) * 3 + 1];
    const float gr = gt_bboxes[(b * NMAX + tgi) * 3 + 2];

    out[OFF_LABELS + idx] = (float)max(gl, 0);
    out[OFF_CIRCLES + (size_t)idx * 3 + 0] = gx;
    out[OFF_CIRCLES + (size_t)idx * 3 + 1] = gy;
    out[OFF_CIRCLES + (size_t)idx * 3 + 2] = gr;
    out[OFF_FG + idx]  = (float)fg;
    out[OFF_TGI + idx] = (float)tgi;
    tgiE[idx] = fg ? tgi : -1;

    float alg = 0.0f;
    if (fg) {
        float ovv = 0.0f;
        float mgv = mask_gt[b * NMAX + tgi];
        float ax = anc[2 * a], ay = anc[2 * a + 1];
        float dx = gx - ax, dy = gy - ay;
        if (mgv > 0.0f && sqrtf(dx * dx + dy * dy) <= gr) {
            float px = pd_circles[(size_t)idx * 3 + 0];
            float py = pd_circles[(size_t)idx * 3 + 1];
            float pr = pd_circles[(size_t)idx * 3 + 2];
            float iou = circle_iou_dev(gx, gy, gr, px, py, pr);
            int lab = min(max(gl, 0), NC - 1);
            float sc = pd_scores[((size_t)b * NA + a) * NC + lab];
            ovv = iou;
            float o2 = iou * iou;
            alg = sc * (o2 * o2 * o2);
        }
        atomicMax(&posal[b * NMAX + tgi], __float_as_uint(alg));
        atomicMax(&posov[b * NMAX + tgi], __float_as_uint(ovv));
    }
    alignv[idx] = alg;
}

// K4: dense write of target_scores — each float4 covers 4 classes of one
// anchor row; bg rows are zero, fg rows have norm at the label slot.
__global__ __launch_bounds__(256) void k4_dense(
    const int* __restrict__ tgiE, const float* __restrict__ alignv,
    const unsigned int* __restrict__ posal, const unsigned int* __restrict__ posov,
    const int* __restrict__ gt_labels, float4* __restrict__ scores4)
{
    const int f = blockIdx.x * 256 + threadIdx.x;     // < 2,688,000
    const int a_idx = f / 20;                         // anchor global idx
    const int p = f - a_idx * 20;                     // float4 slot in row

    float4 v = make_float4(0.f, 0.f, 0.f, 0.f);
    const int tg = tgiE[a_idx];
    if (tg >= 0) {
        const int b = a_idx / NA;
        const float pa = __uint_as_float(posal[b * NMAX + tg]);
        const float po = __uint_as_float(posov[b * NMAX + tg]);
        const float norm = alignv[a_idx] * po / (pa + CEPS);
        const int lab = max(gt_labels[b * NMAX + tg], 0);
        if ((lab >> 2) == p) ((float*)&v)[lab & 3] = norm;
    }
    scores4[f] = v;
}

extern "C" void kernel_launch(void* const* d_in, const int* in_sizes, int n_in,
                              void* d_out, int out_size, void* d_ws, size_t ws_size,
                              hipStream_t stream) {
    const float* pd_scores  = (const float*)d_in[0];
    const float* pd_circles = (const float*)d_in[1];
    const float* anc        = (const float*)d_in[2];
    const int*   gt_labels  = (const int*)d_in[3];
    const float* gt_bboxes  = (const float*)d_in[4];
    const float* mask_gt    = (const float*)d_in[5];
    float* out = (float*)d_out;

    char* ws = (char*)d_ws;
    unsigned long long* colbits = (unsigned long long*)ws;
    unsigned long long* ovkey   = (unsigned long long*)(ws + WS_OVKEY);
    unsigned int* posal = (unsigned int*)(ws + WS_POSAL);
    unsigned int* posov = (unsigned int*)(ws + WS_POSOV);
    int*   tgiE   = (int*)(ws + WS_TGI);
    float* alignv = (float*)(ws + WS_ALIGN);

    k0_zero<<<(ZERO_WS_F4 + 255) / 256, 256, 0, stream>>>((float4*)ws);
    k1_topk<<<BS * NMAX, 256, 0, stream>>>(pd_scores, pd_circles, gt_labels,
                                           gt_bboxes, mask_gt, colbits, ovkey);
    k2_resolve<<<(BS * NA) / 256, 256, 0, stream>>>(pd_scores, pd_circles, anc,
                                                    gt_labels, gt_bboxes, mask_gt,
                                                    colbits, ovkey, out, tgiE,
                                                    alignv, posal, posov);
    k4_dense<<<(BS * NA * NC / 4) / 256, 256, 0, stream>>>(tgiE, alignv, posal,
                                                           posov, gt_labels,
                                                           (float4*)(out + OFF_SCORES));
}